// Round 15
// baseline (263.802 us; speedup 1.0000x reference)
//
#include <hip/hip_runtime.h>
#include <math.h>

#define N_TOKENS 16384
#define D_MODEL  2048
#define NE       64
#define TOPK     8

typedef float f32x4 __attribute__((ext_vector_type(4)));
typedef short s16x8 __attribute__((ext_vector_type(8)));

#define LDSROW 34                     // shorts per x-row (32 data + 2 pad; 17 dwords -> ~2-way banks, conflict-free per R14)
#define PLANE  (16 * LDSROW)          // 544 shorts per split plane
#define XS_BUF (3 * PLANE)            // 1632 shorts per double-buffer half
#define ACC_LD 129                    // fp64 acc row stride

// RNE float->bf16, returns the rounded-back float and the bf16 bits.
__device__ __forceinline__ float bf16_rne(float v, short* s) {
    unsigned u = __float_as_uint(v);
    unsigned r = (u + 0x7fffu + ((u >> 16) & 1u)) & 0xffff0000u;
    *s = (short)(r >> 16);
    return __uint_as_float(r);
}

// Pre-pass (unchanged from R12-R14): B-fragments for [Wg | Wn] (N=128), 3 splits:
// BF[((c*8+ct)*3+s)*64 + l][e] = split_s(W'[c*32 + (l>>4)*8 + e][ct*16 + (l&15)])
__global__ __launch_bounds__(256)
void bf_build(const float* __restrict__ Wg, const float* __restrict__ Wn,
              s16x8* __restrict__ BF) {
    const int id  = blockIdx.x * 256 + threadIdx.x;   // 0..98303
    const int l   = id & 63;
    const int s   = (id >> 6) % 3;
    const int ctc = (id >> 6) / 3;        // c*8 + ct
    const int ct  = ctc & 7;
    const int c   = ctc >> 3;
    const int k0  = c * 32 + (l >> 4) * 8;
    const int col = ct * 16 + (l & 15);
    const float* W = (col < NE) ? (Wg + col) : (Wn + (col - NE));
    s16x8 o;
    #pragma unroll
    for (int e = 0; e < 8; ++e) {
        float v  = W[(size_t)(k0 + e) * NE];
        short h, m, lo;
        float hf = bf16_rne(v, &h);
        float r1 = v - hf;                 // exact
        float mf = bf16_rne(r1, &m);
        float r2 = r1 - mf;                // exact
        bf16_rne(r2, &lo);
        o[e] = (s == 0) ? h : (s == 1) ? m : lo;
    }
    BF[id] = o;
}

// R14 structure (clean pipeline: B reg-prefetch 1 period, x 2 periods, 3 MFMA
// chains, conflict-free LDS) at R13's occupancy (8 waves/SIMD). R14 measured
// 44 VGPRs of true demand < 64-reg budget for 8 waves -> expect no spill.
__global__ __launch_bounds__(512, 8)
void router_mfma(const float* __restrict__ x, const float* __restrict__ eps,
                 const s16x8* __restrict__ BF, const float* __restrict__ bg,
                 const float* __restrict__ bn, float* __restrict__ out_probs,
                 float* __restrict__ out_idx)
{
    __shared__ char smem[16 * ACC_LD * 8];   // 16512 B; xsplit (2x3264 B) aliased
    short*  xsp = (short*)smem;
    double* acc = (double*)smem;

    const int tid  = threadIdx.x;
    const int lane = tid & 63;
    const int wv   = tid >> 6;            // wave id = ctile 0..7 (16 cols each)
    const int row0 = blockIdx.x * 16;

    // ---- convert mapping: one float per thread per 32-k chunk ----
    const int crow = tid >> 5;            // 0..15
    const int ck   = tid & 31;            // 0..31
    const float* xp = x + (size_t)(row0 + crow) * D_MODEL + ck;
    const int cbase = crow * LDSROW + ck;

    auto convert_store = [&](float v, int bb) {
        short h, m, l;
        float hf = bf16_rne(v, &h);
        float r1 = v - hf;                 // exact
        float mf = bf16_rne(r1, &m);
        bf16_rne(r1 - mf, &l);
        short* xb = xsp + bb * XS_BUF;
        xb[cbase]             = h;
        xb[cbase + PLANE]     = m;
        xb[cbase + 2 * PLANE] = l;
    };

    // ---- wave MFMA state ----
    const int abase = (lane & 15) * LDSROW + (lane >> 4) * 8;
    const s16x8* bfp = BF + lane;

    auto loadB = [&](int c, s16x8* dst) {
        #pragma unroll
        for (int s = 0; s < 3; ++s)
            dst[s] = bfp[(size_t)(((c * 8) + wv) * 3 + s) * 64];
    };

    // 3 independent accumulator chains (2 MFMAs each per chunk); folded
    // together every 64 k -> same cadence as R12-R14, regroup only.
    f32x4 Ca = {0.f,0.f,0.f,0.f}, Cb = Ca, Cc = Ca;
    double facc[4] = {0.0, 0.0, 0.0, 0.0};

    auto do_chunk = [&](const s16x8* Bv, int bb) {
        const short* xb = xsp + bb * XS_BUF;
        s16x8 Ah = *(const s16x8*)&xb[abase];
        s16x8 Am = *(const s16x8*)&xb[abase + PLANE];
        s16x8 Al = *(const s16x8*)&xb[abase + 2 * PLANE];
        // interleaved: 3 independent chains, 2-deep each
        Ca = __builtin_amdgcn_mfma_f32_16x16x32_bf16(Am, Bv[1], Ca, 0, 0, 0); // mm
        Cb = __builtin_amdgcn_mfma_f32_16x16x32_bf16(Ah, Bv[2], Cb, 0, 0, 0); // hl
        Cc = __builtin_amdgcn_mfma_f32_16x16x32_bf16(Al, Bv[0], Cc, 0, 0, 0); // lh
        Ca = __builtin_amdgcn_mfma_f32_16x16x32_bf16(Ah, Bv[1], Ca, 0, 0, 0); // hm
        Cb = __builtin_amdgcn_mfma_f32_16x16x32_bf16(Am, Bv[0], Cb, 0, 0, 0); // mh
        Cc = __builtin_amdgcn_mfma_f32_16x16x32_bf16(Ah, Bv[0], Cc, 0, 0, 0); // hh
    };

    #define CONVOY_BARRIER() do {                                   \
        asm volatile("s_waitcnt lgkmcnt(0)" ::: "memory");          \
        __builtin_amdgcn_s_barrier();                               \
        __builtin_amdgcn_sched_barrier(0);                          \
    } while (0)

    // ---- prologue: chunk 0 -> buf0; x 2 periods ahead; B 1 period ahead ----
    s16x8 Bcur[3], Bnext[3];
    convert_store(xp[0], 0);
    float u = xp[32];          // x for chunk 1
    float v = xp[64];          // x for chunk 2
    loadB(0, Bcur);
    loadB(1, Bnext);
    CONVOY_BARRIER();

    // ---- main loop, 2 chunks per iteration ----
    // invariant at top: buf(c&1)=chunk c ready; u=x[c+1]; v=x[c+2];
    //                   Bcur=B[c]; Bnext=B[c+1]
    #pragma unroll 1
    for (int c = 0; c < 64; c += 2) {
        // even body: MFMA chunk c (buf0); convert c+1 -> buf1; prefetch
        convert_store(u, 1);
        u = xp[min(c + 3, 63) * 32];          // x for chunk c+3
        do_chunk(Bcur, 0);
        loadB(min(c + 2, 63), Bcur);          // B for chunk c+2 (in flight over barrier)
        CONVOY_BARRIER();

        // odd body: MFMA chunk c+1 (buf1); convert c+2 -> buf0; prefetch
        convert_store(v, 0);
        v = xp[min(c + 4, 63) * 32];          // x for chunk c+4
        do_chunk(Bnext, 1);
        loadB(min(c + 3, 63), Bnext);         // B for chunk c+3
        #pragma unroll
        for (int j = 0; j < 4; ++j) {         // fp64 fold every 64 k
            facc[j] += (double)Ca[j] + (double)Cb[j] + (double)Cc[j];
            Ca[j] = 0.f; Cb[j] = 0.f; Cc[j] = 0.f;
        }
        CONVOY_BARRIER();
    }

    __syncthreads();   // all LDS reads done before acc overwrites xsplit

    // ---- dump fp64 accs: row = (lane>>4)*4 + j, col = wv*16 + (lane&15) ----
    #pragma unroll
    for (int j = 0; j < 4; ++j)
        acc[(size_t)((lane >> 4) * 4 + j) * ACC_LD + wv * 16 + (lane & 15)] = facc[j];
    __syncthreads();

    // ---- epilogue (identical numerics to R2-R14): 2 tokens per wave ----
    const float bgv = bg[lane];
    const float bnv = bn[lane];

    #pragma unroll 1
    for (int q = 0; q < 2; ++q) {
        const int tt  = wv * 2 + q;
        const int tok = row0 + tt;
        const double logit = acc[(size_t)tt * ACC_LD + lane] + (double)bgv;
        const double nvv   = acc[(size_t)tt * ACC_LD + 64 + lane] + (double)bnv;
        const double sp    = (nvv > 0.0) ? (nvv + log1p(exp(-nvv))) : log1p(exp(nvv));
        const double noisy = logit + (double)eps[(size_t)tok * NE + lane] * sp;

        // iterative top-8; tie-break: higher value, then lower index (lax.top_k)
        double cur = noisy;
        double m = 0.0, sum = 0.0;
        int    sel = 0;
        float  my_idx = 0.0f;
        #pragma unroll
        for (int rk = 0; rk < TOPK; ++rk) {
            double bv = cur;
            int    bi = lane;
            #pragma unroll
            for (int off = 32; off >= 1; off >>= 1) {
                double ov = __shfl_xor(bv, off);
                int    oi = __shfl_xor(bi, off);
                if (ov > bv || (ov == bv && oi < bi)) { bv = ov; bi = oi; }
            }
            if (rk == 0) m = bv;
            sum += exp(bv - m);
            if (lane == bi) { sel = 1; cur = -INFINITY; }
            if (lane == rk) my_idx = (float)bi;
        }

        out_probs[(size_t)tok * NE + lane] = (float)(sel ? exp(noisy - m) / sum : 0.0);
        if (lane < TOPK) out_idx[(size_t)tok * TOPK + lane] = my_idx;
    }
}

extern "C" void kernel_launch(void* const* d_in, const int* in_sizes, int n_in,
                              void* d_out, int out_size, void* d_ws, size_t ws_size,
                              hipStream_t stream) {
    const float* x   = (const float*)d_in[0];
    const float* eps = (const float*)d_in[1];
    const float* Wg  = (const float*)d_in[2];
    const float* bg  = (const float*)d_in[3];
    const float* Wn  = (const float*)d_in[4];
    const float* bn  = (const float*)d_in[5];

    float* out_probs = (float*)d_out;                              // [N, E]
    float* out_idx   = (float*)d_out + (size_t)N_TOKENS * NE;      // [N, K]

    s16x8* BF = (s16x8*)d_ws;    // 98304 * 16 B = 1.5 MB of B-fragments

    bf_build<<<dim3(384), dim3(256), 0, stream>>>(Wg, Wn, BF);

    router_mfma<<<dim3(N_TOKENS / 16), dim3(512), 0, stream>>>(
        x, eps, BF, bg, bn, out_probs, out_idx);
}

// Round 16
// 168.588 us; speedup vs baseline: 1.5648x; 1.5648x over previous
//
#include <hip/hip_runtime.h>
#include <hip/hip_fp16.h>
#include <math.h>

#define N_TOKENS 16384
#define D_MODEL  2048
#define NE       64
#define TOPK     8

typedef float    f32x4 __attribute__((ext_vector_type(4)));
typedef _Float16 f16x8 __attribute__((ext_vector_type(8)));
typedef short    s16x8 __attribute__((ext_vector_type(8)));

#define LDSROW 34                  // shorts per x-row (32 data + 2 pad; conflict-free per R14)
#define PLANE  (16 * LDSROW)       // 544 shorts per split plane
#define CH_BUF (2 * PLANE)         // one chunk buffer = h-plane + m-plane
#define ACC_LD 129                 // fp64 acc row stride
#define WSCL   512.0f              // B pre-scale (keeps Bm out of f16 denormals)
#define XSCL   1024.0f             // x pre-scale (keeps Am out of f16 denormals)
#define UNSCL  (1.0 / (1024.0 * 512.0))   // exact 2^-19

// Pre-pass: B-fragments for [Wg | Wn] (N=128), 2 fp16 splits of W*512:
// BF[((c*8+ct)*2+s)*64 + l][e] = split_s(512*W'[c*32 + (l>>4)*8 + e][ct*16 + (l&15)])
__global__ __launch_bounds__(256)
void bf_build(const float* __restrict__ Wg, const float* __restrict__ Wn,
              s16x8* __restrict__ BF) {
    const int id  = blockIdx.x * 256 + threadIdx.x;   // 0..65535
    const int l   = id & 63;
    const int s   = (id >> 6) & 1;
    const int ctc = id >> 7;          // c*8 + ct
    const int ct  = ctc & 7;
    const int c   = ctc >> 3;
    const int k0  = c * 32 + (l >> 4) * 8;
    const int col = ct * 16 + (l & 15);
    const float* W = (col < NE) ? (Wg + col) : (Wn + (col - NE));
    s16x8 o;
    #pragma unroll
    for (int e = 0; e < 8; ++e) {
        float v  = W[(size_t)(k0 + e) * NE] * WSCL;
        __half h = __float2half(v);                    // RNE
        if (s == 0) o[e] = __half_as_short(h);
        else        o[e] = __half_as_short(__float2half(v - __half2float(h)));  // exact resid
    }
    BF[id] = o;
}

__global__ __launch_bounds__(512, 6)
void router_mfma(const float* __restrict__ x, const float* __restrict__ eps,
                 const s16x8* __restrict__ BF, const float* __restrict__ bg,
                 const float* __restrict__ bn, float* __restrict__ out_probs,
                 float* __restrict__ out_idx)
{
    __shared__ char smem[16 * ACC_LD * 8];   // 16512 B; x quad-buffer (8704 B) aliased
    short*  xsp = (short*)smem;
    double* acc = (double*)smem;

    const int tid  = threadIdx.x;
    const int lane = tid & 63;
    const int wv   = tid >> 6;            // wave id = ctile 0..7
    const int row0 = blockIdx.x * 16;

    // ---- convert mapping: one float per thread per 32-k chunk ----
    const int crow = tid >> 5;            // 0..15
    const int ck   = tid & 31;            // 0..31
    const float* xp = x + (size_t)(row0 + crow) * D_MODEL + ck;
    const int cbase = crow * LDSROW + ck;

    auto convert_store = [&](float vf, int c) {
        float v  = vf * XSCL;                          // exact pow2 scale
        __half h = __float2half(v);                    // RNE
        float  r = v - __half2float(h);                // exact (Sterbenz)
        __half m = __float2half(r);
        short* xb = xsp + (c & 3) * CH_BUF;
        xb[cbase]         = __half_as_short(h);
        xb[cbase + PLANE] = __half_as_short(m);
    };

    // ---- wave MFMA state ----
    const int abase = (lane & 15) * LDSROW + (lane >> 4) * 8;
    const f16x8* bfp = (const f16x8*)BF + lane;

    auto loadB = [&](int c, f16x8& bh, f16x8& bm) {
        const f16x8* p = bfp + (size_t)((c * 8 + wv) * 2) * 64;
        bh = p[0];
        bm = p[64];
    };

    // 2 accumulator chains; 3 MFMA terms per chunk (hh, hm, mh — mm/hl/lh are
    // below 2^-23 rel with the pow2 pre-scales). fp64 fold every 64 k.
    f32x4 Ca = {0.f,0.f,0.f,0.f}, Cb = Ca;
    double facc[4] = {0.0, 0.0, 0.0, 0.0};

    auto do_chunk = [&](f16x8 Bh, f16x8 Bm, int c) {
        const short* xb = xsp + (c & 3) * CH_BUF;
        f16x8 Ah = *(const f16x8*)&xb[abase];
        f16x8 Am = *(const f16x8*)&xb[abase + PLANE];
        Ca = __builtin_amdgcn_mfma_f32_16x16x32_f16(Am, Bh, Ca, 0, 0, 0); // mh (small first)
        Cb = __builtin_amdgcn_mfma_f32_16x16x32_f16(Ah, Bm, Cb, 0, 0, 0); // hm
        Ca = __builtin_amdgcn_mfma_f32_16x16x32_f16(Ah, Bh, Ca, 0, 0, 0); // hh
    };

    #define CONVOY_BARRIER() do {                                   \
        asm volatile("s_waitcnt lgkmcnt(0)" ::: "memory");          \
        __builtin_amdgcn_s_barrier();                               \
        __builtin_amdgcn_sched_barrier(0);                          \
    } while (0)

    // ---- prologue: chunks 0,1 -> bufs 0,1; x for 2,3 in regs; B for 0,1 ----
    f16x8 B0h,B0m,B1h,B1m,B2h,B2m,B3h,B3m;
    float u0, u1, u2, u3;
    convert_store(xp[0], 0);
    convert_store(xp[32], 1);
    u0 = xp[2 * 32]; u1 = xp[3 * 32];
    loadB(0, B0h, B0m); loadB(1, B1h, B1m);
    CONVOY_BARRIER();

    // ---- main loop: 16 iterations x 2 periods; each period = 2 chunks,
    //      one barrier. Quad-buffer: period reads bufs c,c+1 while writing
    //      c+2,c+3. Clamped tail ops rewrite identical data (benign). ----
    #pragma unroll 1
    for (int m = 0; m < 64; m += 4) {
        // period A: compute m,m+1; convert m+2,m+3; B-load m+2,m+3; x-prefetch m+4,m+5
        loadB(min(m + 2, 63), B2h, B2m);
        loadB(min(m + 3, 63), B3h, B3m);
        u2 = xp[min(m + 4, 63) * 32];
        u3 = xp[min(m + 5, 63) * 32];
        convert_store(u0, m + 2);
        convert_store(u1, m + 3);
        do_chunk(B0h, B0m, m);
        do_chunk(B1h, B1m, m + 1);
        #pragma unroll
        for (int j = 0; j < 4; ++j) { facc[j] += (double)Ca[j] + (double)Cb[j]; Ca[j] = 0.f; Cb[j] = 0.f; }
        CONVOY_BARRIER();

        // period B: compute m+2,m+3; convert m+4,m+5; B-load m+4,m+5; x-prefetch m+6,m+7
        loadB(min(m + 4, 63), B0h, B0m);
        loadB(min(m + 5, 63), B1h, B1m);
        u0 = xp[min(m + 6, 63) * 32];
        u1 = xp[min(m + 7, 63) * 32];
        convert_store(u2, min(m + 4, 63));
        convert_store(u3, min(m + 5, 63));
        do_chunk(B2h, B2m, m + 2);
        do_chunk(B3h, B3m, m + 3);
        #pragma unroll
        for (int j = 0; j < 4; ++j) { facc[j] += (double)Ca[j] + (double)Cb[j]; Ca[j] = 0.f; Cb[j] = 0.f; }
        CONVOY_BARRIER();
    }

    __syncthreads();   // all LDS reads done before acc overwrites x-buffers

    // ---- dump fp64 accs (unscale by exact 2^-19):
    //      row = (lane>>4)*4 + j, col = wv*16 + (lane&15) ----
    #pragma unroll
    for (int j = 0; j < 4; ++j)
        acc[(size_t)((lane >> 4) * 4 + j) * ACC_LD + wv * 16 + (lane & 15)] = facc[j] * UNSCL;
    __syncthreads();

    // ---- epilogue (identical numerics to R2-R15): 2 tokens per wave ----
    const float bgv = bg[lane];
    const float bnv = bn[lane];

    #pragma unroll 1
    for (int q = 0; q < 2; ++q) {
        const int tt  = wv * 2 + q;
        const int tok = row0 + tt;
        const double logit = acc[(size_t)tt * ACC_LD + lane] + (double)bgv;
        const double nvv   = acc[(size_t)tt * ACC_LD + 64 + lane] + (double)bnv;
        const double sp    = (nvv > 0.0) ? (nvv + log1p(exp(-nvv))) : log1p(exp(nvv));
        const double noisy = logit + (double)eps[(size_t)tok * NE + lane] * sp;

        // iterative top-8; tie-break: higher value, then lower index (lax.top_k)
        double cur = noisy;
        double m = 0.0, sum = 0.0;
        int    sel = 0;
        float  my_idx = 0.0f;
        #pragma unroll
        for (int rk = 0; rk < TOPK; ++rk) {
            double bv = cur;
            int    bi = lane;
            #pragma unroll
            for (int off = 32; off >= 1; off >>= 1) {
                double ov = __shfl_xor(bv, off);
                int    oi = __shfl_xor(bi, off);
                if (ov > bv || (ov == bv && oi < bi)) { bv = ov; bi = oi; }
            }
            if (rk == 0) m = bv;
            sum += exp(bv - m);
            if (lane == bi) { sel = 1; cur = -INFINITY; }
            if (lane == rk) my_idx = (float)bi;
        }

        out_probs[(size_t)tok * NE + lane] = (float)(sel ? exp(noisy - m) / sum : 0.0);
        if (lane < TOPK) out_idx[(size_t)tok * TOPK + lane] = my_idx;
    }
}

extern "C" void kernel_launch(void* const* d_in, const int* in_sizes, int n_in,
                              void* d_out, int out_size, void* d_ws, size_t ws_size,
                              hipStream_t stream) {
    const float* x   = (const float*)d_in[0];
    const float* eps = (const float*)d_in[1];
    const float* Wg  = (const float*)d_in[2];
    const float* bg  = (const float*)d_in[3];
    const float* Wn  = (const float*)d_in[4];
    const float* bn  = (const float*)d_in[5];

    float* out_probs = (float*)d_out;                              // [N, E]
    float* out_idx   = (float*)d_out + (size_t)N_TOKENS * NE;      // [N, K]

    s16x8* BF = (s16x8*)d_ws;    // 65536 * 16 B = 1 MB of B-fragments

    bf_build<<<dim3(256), dim3(256), 0, stream>>>(Wg, Wn, BF);

    router_mfma<<<dim3(N_TOKENS / 16), dim3(512), 0, stream>>>(
        x, eps, BF, bg, bn, out_probs, out_idx);
}

// Round 17
// 164.634 us; speedup vs baseline: 1.6024x; 1.0240x over previous
//
#include <hip/hip_runtime.h>
#include <hip/hip_fp16.h>
#include <math.h>

#define N_TOKENS 16384
#define D_MODEL  2048
#define NE       64
#define TOPK     8

typedef float    f32x4 __attribute__((ext_vector_type(4)));
typedef _Float16 f16x8 __attribute__((ext_vector_type(8)));
typedef short    s16x8 __attribute__((ext_vector_type(8)));

#define LDSROW 34                  // shorts per x-row (32 data + 2 pad; conflict-free per R14/R16)
#define PLANE  (16 * LDSROW)       // 544 shorts per split plane
#define CH_BUF (2 * PLANE)         // one chunk buffer = h-plane + m-plane (1088 shorts)
#define WSCL   512.0f              // B pre-scale (keeps Bm out of f16 denormals)
#define XSCL   1024.0f             // x pre-scale (keeps Am out of f16 denormals)
#define UNSCL  (1.0 / (1024.0 * 512.0))   // exact 2^-19

// Pre-pass (validated R16): B-fragments for [Wg | Wn] (N=128), 2 fp16 splits of W*512:
// BF[((c*8+ct)*2+s)*64 + l][e] = split_s(512*W'[c*32 + (l>>4)*8 + e][ct*16 + (l&15)])
__global__ __launch_bounds__(256)
void bf_build(const float* __restrict__ Wg, const float* __restrict__ Wn,
              s16x8* __restrict__ BF) {
    const int id  = blockIdx.x * 256 + threadIdx.x;   // 0..65535
    const int l   = id & 63;
    const int s   = (id >> 6) & 1;
    const int ctc = id >> 7;          // c*8 + ct
    const int ct  = ctc & 7;
    const int c   = ctc >> 3;
    const int k0  = c * 32 + (l >> 4) * 8;
    const int col = ct * 16 + (l & 15);
    const float* W = (col < NE) ? (Wg + col) : (Wn + (col - NE));
    s16x8 o;
    #pragma unroll
    for (int e = 0; e < 8; ++e) {
        float v  = W[(size_t)(k0 + e) * NE] * WSCL;
        __half h = __float2half(v);                    // RNE
        if (s == 0) o[e] = __half_as_short(h);
        else        o[e] = __half_as_short(__float2half(v - __half2float(h)));  // exact resid
    }
    BF[id] = o;
}

// ---------------- Kernel A: pure GEMM, no epilogue ----------------
// Lean register footprint (B ring 16 + acc 8 + facc 8 + misc ~20 < 64)
// so (512,8) holds WITHOUT the allocator squeeze-spill seen in R8/R13/R15/R16
// (the fp64 top-8 epilogue was the demand monster -> moved to kernel B).
__global__ __launch_bounds__(512, 8)
void router_gemm(const float* __restrict__ x, const s16x8* __restrict__ BF,
                 float* __restrict__ dots)    // [N_TOKENS][128] fp32
{
    __shared__ short xsp[4 * CH_BUF];     // 8704 B: quad-buffered x splits

    const int tid  = threadIdx.x;
    const int lane = tid & 63;
    const int wv   = tid >> 6;            // wave id = ctile 0..7 (16 cols each)
    const int row0 = blockIdx.x * 16;

    // ---- convert mapping: one float per thread per 32-k chunk ----
    const int crow = tid >> 5;            // 0..15
    const int ck   = tid & 31;            // 0..31
    const float* xp = x + (size_t)(row0 + crow) * D_MODEL + ck;
    const int cbase = crow * LDSROW + ck;

    auto convert_store = [&](float vf, int c) {
        float v  = vf * XSCL;                          // exact pow2 scale
        __half h = __float2half(v);                    // RNE
        float  r = v - __half2float(h);                // exact (Sterbenz)
        __half m = __float2half(r);
        short* xb = xsp + (c & 3) * CH_BUF;
        xb[cbase]         = __half_as_short(h);
        xb[cbase + PLANE] = __half_as_short(m);
    };

    // ---- wave MFMA state ----
    const int abase = (lane & 15) * LDSROW + (lane >> 4) * 8;
    const f16x8* bfp = (const f16x8*)BF + lane;

    auto loadB = [&](int c, f16x8& bh, f16x8& bm) {
        const f16x8* p = bfp + (size_t)((c * 8 + wv) * 2) * 64;
        bh = p[0];
        bm = p[64];
    };

    f32x4 Ca = {0.f,0.f,0.f,0.f}, Cb = Ca;
    double facc[4] = {0.0, 0.0, 0.0, 0.0};

    auto do_chunk = [&](f16x8 Bh, f16x8 Bm, int c) {
        const short* xb = xsp + (c & 3) * CH_BUF;
        f16x8 Ah = *(const f16x8*)&xb[abase];
        f16x8 Am = *(const f16x8*)&xb[abase + PLANE];
        Ca = __builtin_amdgcn_mfma_f32_16x16x32_f16(Am, Bh, Ca, 0, 0, 0); // mh (small first)
        Cb = __builtin_amdgcn_mfma_f32_16x16x32_f16(Ah, Bm, Cb, 0, 0, 0); // hm
        Ca = __builtin_amdgcn_mfma_f32_16x16x32_f16(Ah, Bh, Ca, 0, 0, 0); // hh
    };

    #define CONVOY_BARRIER() do {                                   \
        asm volatile("s_waitcnt lgkmcnt(0)" ::: "memory");          \
        __builtin_amdgcn_s_barrier();                               \
        __builtin_amdgcn_sched_barrier(0);                          \
    } while (0)

    // ---- prologue: chunks 0,1 -> bufs 0,1; B ring holds chunks 0,1 ----
    f16x8 BAh, BAm, BBh, BBm;
    convert_store(xp[0], 0);
    convert_store(xp[32], 1);
    float u0 = xp[2 * 32], u1 = xp[3 * 32];
    loadB(0, BAh, BAm);
    loadB(1, BBh, BBm);
    CONVOY_BARRIER();

    // ---- main loop: 32 periods x 2 chunks, one barrier per period.
    //      Quad-buffer: period reads bufs c,c+1 while writing c+2,c+3
    //      (buf (c+2)&3 was last read two barriers ago -> safe).
    //      B ring: consume then immediately re-load 2 chunks ahead.
    #pragma unroll 1
    for (int m = 0; m < 64; m += 2) {
        do_chunk(BAh, BAm, m);
        loadB(min(m + 2, 63), BAh, BAm);      // in flight across the barrier
        convert_store(u0, m + 2);
        do_chunk(BBh, BBm, m + 1);
        loadB(min(m + 3, 63), BBh, BBm);
        convert_store(u1, m + 3);
        u0 = xp[min(m + 4, 63) * 32];
        u1 = xp[min(m + 5, 63) * 32];
        #pragma unroll
        for (int j = 0; j < 4; ++j) {         // fp64 fold every 64 k (same cadence R12-R16)
            facc[j] += (double)Ca[j] + (double)Cb[j];
            Ca[j] = 0.f; Cb[j] = 0.f;
        }
        CONVOY_BARRIER();
    }

    // ---- write fp32 dots (unscale by exact 2^-19) ----
    // row = (lane>>4)*4 + j, col = wv*16 + (lane&15); 16-lane groups write
    // 16 consecutive dwords per row.
    const int ocol = wv * 16 + (lane & 15);
    #pragma unroll
    for (int j = 0; j < 4; ++j)
        dots[(size_t)(row0 + (lane >> 4) * 4 + j) * 128 + ocol]
            = (float)(facc[j] * UNSCL);
}

// ---------------- Kernel B: softplus + noise + top-8 + sparse softmax ----------------
// One wave per token; fp64 path identical to the R2-R16 validated epilogue.
__global__ __launch_bounds__(512)
void router_topk(const float* __restrict__ dots, const float* __restrict__ eps,
                 const float* __restrict__ bg, const float* __restrict__ bn,
                 float* __restrict__ out_probs, float* __restrict__ out_idx)
{
    const int tid  = threadIdx.x;
    const int lane = tid & 63;
    const int wv   = tid >> 6;
    const int tok  = blockIdx.x * 8 + wv;

    const double logit = (double)dots[(size_t)tok * 128 + lane]      + (double)bg[lane];
    const double nvv   = (double)dots[(size_t)tok * 128 + 64 + lane] + (double)bn[lane];
    const double sp    = (nvv > 0.0) ? (nvv + log1p(exp(-nvv))) : log1p(exp(nvv));
    const double noisy = logit + (double)eps[(size_t)tok * NE + lane] * sp;

    // iterative top-8; tie-break: higher value, then lower index (lax.top_k)
    double cur = noisy;
    double m = 0.0, sum = 0.0;
    int    sel = 0;
    float  my_idx = 0.0f;
    #pragma unroll
    for (int rk = 0; rk < TOPK; ++rk) {
        double bv = cur;
        int    bi = lane;
        #pragma unroll
        for (int off = 32; off >= 1; off >>= 1) {
            double ov = __shfl_xor(bv, off);
            int    oi = __shfl_xor(bi, off);
            if (ov > bv || (ov == bv && oi < bi)) { bv = ov; bi = oi; }
        }
        if (rk == 0) m = bv;
        sum += exp(bv - m);
        if (lane == bi) { sel = 1; cur = -INFINITY; }
        if (lane == rk) my_idx = (float)bi;
    }

    out_probs[(size_t)tok * NE + lane] = (float)(sel ? exp(noisy - m) / sum : 0.0);
    if (lane < TOPK) out_idx[(size_t)tok * TOPK + lane] = my_idx;
}

extern "C" void kernel_launch(void* const* d_in, const int* in_sizes, int n_in,
                              void* d_out, int out_size, void* d_ws, size_t ws_size,
                              hipStream_t stream) {
    const float* x   = (const float*)d_in[0];
    const float* eps = (const float*)d_in[1];
    const float* Wg  = (const float*)d_in[2];
    const float* bg  = (const float*)d_in[3];
    const float* Wn  = (const float*)d_in[4];
    const float* bn  = (const float*)d_in[5];

    float* out_probs = (float*)d_out;                              // [N, E]
    float* out_idx   = (float*)d_out + (size_t)N_TOKENS * NE;      // [N, K]

    // d_ws layout: BF fragments (1 MB) | dots fp32 [16384][128] (8 MB)
    s16x8* BF   = (s16x8*)d_ws;
    float* dots = (float*)((char*)d_ws + (size_t)65536 * 16);

    bf_build<<<dim3(256), dim3(256), 0, stream>>>(Wg, Wn, BF);

    router_gemm<<<dim3(N_TOKENS / 16), dim3(512), 0, stream>>>(x, BF, dots);

    router_topk<<<dim3(N_TOKENS / 8), dim3(512), 0, stream>>>(
        dots, eps, bg, bn, out_probs, out_idx);
}